// Round 11
// baseline (60.815 us; speedup 1.0000x reference)
//
#include <hip/hip_runtime.h>

// SSIM map — round-11: persistent column strip + ring LDS, NO reg prefetch.
// B=16, C=3, H=W=512, 11-tap separable gaussian (sigma=1.5).
//
// One block = one 32x512 strip of one channel. Grid 16x1x48 = 768 blocks =
// exactly 3/CU. XCD swizzle: tile=(lin%8)*96+lin/8 -> each XCD owns 6 whole
// channels (round-9's win, FETCH at compulsory).
//
// Ring: union LDS [74][164]f, slot(row)=(row+5)%74 (round-8's indexing,
// correctness-verified there). Per chunk k (64 output rows):
//   S3(k): v-conv+SSIM from ring hf (8-row fat items, 256 thr, paired xy)
//   bar; S1: stage 64 new raw rows global->reg->LDS IN ONE PHASE
//   bar; S2: h-conv the 64 new rows in place (8-col items, 4 waves)
//   bar.
// Prologue: stage+h-conv rows -5..68 (slots 0..73) = round-10 stage1/2.
//
// Round-8 post-mortem REVISED: its +93MB WRITE was cross-barrier float4
// prefetch payloads demoted to SCRATCH (VGPR_Count stayed 40 — localMem,
// rule #20), not occupancy spills. This round keeps ZERO fp state across
// barriers. Tripwire: WRITE_SIZE must stay 49MB.
//
// Gain: staging 522 rows/strip vs 592 (-12% S1+S2 work; y-halo re-staging
// eliminated). Accumulation order identical -> bitwise-same output.

#define Wd    512
#define Hd    512
#define BC    48
#define TX    32
#define RS    74          // ring slots (64 chunk + 10 halo)
#define IC4   12          // float4 cols staged per row (48 cols: c0-8..c0+39)
#define PITCH 164         // floats/row: 656B = 41 float4s (odd: bank stagger)
#define NT    512

__device__ __forceinline__ float2 pk_mul2(float2 a, float2 b) {
    float2 d;
    asm("v_pk_mul_f32 %0, %1, %2" : "=v"(d) : "v"(a), "v"(b));
    return d;
}
// acc = w*v + acc  (both lanes); w uniform -> SGPR pair
__device__ __forceinline__ void pk_fma2(float2& acc, float2 w, float2 v) {
    asm("v_pk_fma_f32 %0, %1, %2, %0" : "+v"(acc) : "s"(w), "v"(v));
}
// gaussian weight with zero padding outside [0,10] (compile-time folded)
__device__ __forceinline__ float gwf(const float* g, int m) {
    return (m >= 0 && m <= 10) ? g[m] : 0.f;
}

// 8-col horizontal conv of one raw row slot (in-place union write).
// Identical math/order to round-10 stage 2 (bitwise-same).
__device__ __forceinline__ void hconv8(float (*buf)[PITCH], const float* g,
                                       int row, int cb) {
    const float* __restrict__ rb = &buf[row][2 * cb + 4];

    float2 A01[8], A23[8], A4p[4];
#pragma unroll
    for (int j = 0; j < 8; ++j) {
        A01[j] = make_float2(0.f, 0.f);
        A23[j] = make_float2(0.f, 0.f);
    }
#pragma unroll
    for (int p = 0; p < 4; ++p) A4p[p] = make_float2(0.f, 0.f);

    float4 q4[10];
#pragma unroll
    for (int q = 0; q < 5; ++q)                  // batch A
        q4[q] = *reinterpret_cast<const float4*>(rb + 4 * q);
#pragma unroll
    for (int kk = 0; kk < 8; ++kk) {
        const float4 f = q4[(kk + 1) >> 1];
        const float2 vv = (kk & 1) ? make_float2(f.x, f.y)
                                   : make_float2(f.z, f.w);
        const float2 pp   = pk_mul2(vv, vv);
        const float  pxy  = vv.x * vv.y;
        const float2 pxy2 = make_float2(pxy, pxy);
#pragma unroll
        for (int j = 0; j < 8; ++j) {
            const int m = kk - j;
            if (m >= 0 && m <= 10) {
                const float2 w2 = make_float2(g[m], g[m]);
                pk_fma2(A01[j], w2, vv);
                pk_fma2(A23[j], w2, pp);
            }
        }
#pragma unroll
        for (int p = 0; p < 4; ++p) {
            const int m0 = kk - (p << 1);
            if (m0 >= 0 && m0 <= 11) {
                const float2 w2 = make_float2(gwf(g, m0), gwf(g, m0 - 1));
                pk_fma2(A4p[p], w2, pxy2);
            }
        }
    }
#pragma unroll
    for (int q = 5; q < 10; ++q)                 // batch B
        q4[q] = *reinterpret_cast<const float4*>(rb + 4 * q);
#pragma unroll
    for (int kk = 8; kk < 18; ++kk) {
        const float4 f = q4[(kk + 1) >> 1];
        const float2 vv = (kk & 1) ? make_float2(f.x, f.y)
                                   : make_float2(f.z, f.w);
        const float2 pp   = pk_mul2(vv, vv);
        const float  pxy  = vv.x * vv.y;
        const float2 pxy2 = make_float2(pxy, pxy);
#pragma unroll
        for (int j = 0; j < 8; ++j) {
            const int m = kk - j;
            if (m >= 0 && m <= 10) {
                const float2 w2 = make_float2(g[m], g[m]);
                pk_fma2(A01[j], w2, vv);
                pk_fma2(A23[j], w2, pp);
            }
        }
#pragma unroll
        for (int p = 0; p < 4; ++p) {
            const int m0 = kk - (p << 1);
            if (m0 >= 0 && m0 <= 11) {
                const float2 w2 = make_float2(gwf(g, m0), gwf(g, m0 - 1));
                pk_fma2(A4p[p], w2, pxy2);
            }
        }
    }
#pragma unroll
    for (int j = 0; j < 8; ++j) {
        *reinterpret_cast<float4*>(&buf[row][4 * (cb + j)]) =
            make_float4(A01[j].x, A01[j].y, A23[j].x, A23[j].y);
    }
    *reinterpret_cast<float4*>(&buf[row][128 + cb]) =
        make_float4(A4p[0].x, A4p[0].y, A4p[1].x, A4p[1].y);
    *reinterpret_cast<float4*>(&buf[row][128 + cb + 4]) =
        make_float4(A4p[2].x, A4p[2].y, A4p[3].x, A4p[3].y);
}

__global__ __launch_bounds__(NT, 6) void ssim_kernel(
    const float* __restrict__ x, const float* __restrict__ y,
    float* __restrict__ out)
{
    __shared__ __align__(16) float buf[RS][PITCH];   // 48544 B -> 3 blocks/CU

    // fp32-normalized gaussian, sigma=1.5, K=11 (matches np reference ~1e-7)
    const float g[11] = {
        0.00102838f, 0.00759875f, 0.03600077f, 0.10936069f, 0.21300553f,
        0.26601172f,
        0.21300553f, 0.10936069f, 0.03600077f, 0.00759875f, 0.00102838f};

    const int tid = threadIdx.x;

    // ---- XCD swizzle over 768 strips: each XCD owns 6 whole channels ----
    const int lin  = blockIdx.x + (blockIdx.z << 4);   // 0..767
    const int tile = ((lin & 7) * 96) + (lin >> 3);    // bijective, 768=8*96
    const int bc   = tile >> 4;                        // channel 0..47
    const int txi  = tile & 15;                        // strip col 0..15
    const int c0   = txi * TX;

    const float* __restrict__ xp = x + (size_t)bc * Hd * Wd;
    const float* __restrict__ yp = y + (size_t)bc * Hd * Wd;
    float* __restrict__ op = out + (size_t)bc * Hd * Wd;

    const bool xin = (txi > 0) && (txi < (Wd / TX) - 1);

    // ---- Prologue S1: rows -5..68 -> slots 0..73 ----
#pragma unroll
    for (int it = 0; it < 2; ++it) {
        const int idx = tid + it * NT;
        if (idx < RS * IC4) {
            const int r  = idx / IC4;
            const int c4 = idx - r * IC4;
            const int gr = r - 5;
            const int gc = c0 - 8 + 4 * c4;
            const bool ok = (gr >= 0) && (xin || (unsigned)gc < (unsigned)Wd);
            float4 lx = make_float4(0.f, 0.f, 0.f, 0.f), ly = lx;
            if (ok) {
                const size_t gi = ((size_t)gr << 9) + gc;
                lx = *reinterpret_cast<const float4*>(xp + gi);
                ly = *reinterpret_cast<const float4*>(yp + gi);
            }
            *reinterpret_cast<float4*>(&buf[r][8 * c4]) =
                make_float4(lx.x, ly.x, lx.y, ly.y);
            *reinterpret_cast<float4*>(&buf[r][8 * c4 + 4]) =
                make_float4(lx.z, ly.z, lx.w, ly.w);
        }
    }
    __syncthreads();

    // ---- Prologue S2: h-conv slots 0..73 (296 items, 5-wave map) ----
    {
        const int l = tid & 63, wid = tid >> 6;
        int row, cg;
        if (wid < 4) { row = (wid << 4) + ((l >> 5) << 3) + (l & 7); cg = (l >> 3) & 3; }
        else         { row = 64 + (l >> 2);                          cg = l & 3; }
        if ((wid < 4) || (wid == 4 && l < 40))
            hconv8(buf, g, row, cg << 3);
    }
    __syncthreads();

    // ---- hoisted invariants (ints only — no fp state across barriers) ----
    const int tx = tid & 31;
    const int og = (tid >> 5) << 3;              // S3 row group 0,8,..,56 (tid<256)
    const int i_row0 = tid / IC4, c40 = tid - i_row0 * IC4;
    const int i_row1 = (tid + NT) / IC4, c41 = (tid + NT) - i_row1 * IC4;
    const int  gc0 = c0 - 8 + 4 * c40;
    const int  gc1 = c0 - 8 + 4 * c41;
    const bool okc0 = xin || (unsigned)gc0 < (unsigned)Wd;
    const bool okc1 = xin || (unsigned)gc1 < (unsigned)Wd;
    const int l6 = tid & 63;
    const int s2row = ((tid >> 6) & 3) * 16 + ((l6 >> 5) << 3) + (l6 & 7);
    const int s2cb  = ((l6 >> 3) & 3) << 3;

    int base74 = 0;                  // (64k) mod 74
    int growb  = 69;                 // first global row staged for chunk k+1
    int orow   = og;                 // output row base (64k + og)

#pragma unroll 1
    for (int k = 0; k < 8; ++k) {
        // ---- S3: v-conv + SSIM, out rows orow..orow+7 (256 threads) ----
        if (tid < 256) {
            int bb = base74 + og; if (bb >= RS) bb -= RS;
            const float* p4  = &buf[0][0] + bb * PITCH + 4 * tx;
            const float* px_ = &buf[0][0] + bb * PITCH + 128 + tx;

            float2 acc01[8], acc23[8], acc4p[4];
#pragma unroll
            for (int j = 0; j < 8; ++j) {
                acc01[j] = make_float2(0.f, 0.f);
                acc23[j] = make_float2(0.f, 0.f);
            }
#pragma unroll
            for (int p = 0; p < 4; ++p) acc4p[p] = make_float2(0.f, 0.f);

#pragma unroll
            for (int rr = 0; rr < 18; ++rr) {
                const int sub = ((bb + rr) >= RS) ? RS * PITCH : 0;  // ring wrap
                const float4 h4 =
                    *reinterpret_cast<const float4*>(p4 + rr * PITCH - sub);
                const float  h5 = *(px_ + rr * PITCH - sub);
                const float2 h01 = make_float2(h4.x, h4.y);
                const float2 h23 = make_float2(h4.z, h4.w);
                const float2 h55 = make_float2(h5, h5);
#pragma unroll
                for (int j = 0; j < 8; ++j) {
                    const int m = rr - j;
                    if (m >= 0 && m <= 10) {
                        const float2 w2 = make_float2(g[m], g[m]);
                        pk_fma2(acc01[j], w2, h01);
                        pk_fma2(acc23[j], w2, h23);
                    }
                }
#pragma unroll
                for (int p = 0; p < 4; ++p) {
                    const int m0 = rr - (p << 1);
                    if (m0 >= 0 && m0 <= 11) {
                        const float2 w2 = make_float2(gwf(g, m0), gwf(g, m0 - 1));
                        pk_fma2(acc4p[p], w2, h55);
                    }
                }
            }
#pragma unroll
            for (int j = 0; j < 8; ++j) {
                const float2 a01  = acc01[j];
                const float2 musq = pk_mul2(a01, a01);   // (mu1^2, mu2^2)
                const float  mu12 = a01.x * a01.y;
                const float  a4   = (j & 1) ? acc4p[j >> 1].y : acc4p[j >> 1].x;
                const float  s1   = acc23[j].x - musq.x;
                const float  s2   = acc23[j].y - musq.y;
                const float  s12  = a4 - mu12;
                const float num = fmaf(2.f, mu12, 1e-4f) * fmaf(2.f, s12, 9e-4f);
                const float den = ((musq.x + musq.y) + 1e-4f) * ((s1 + s2) + 9e-4f);
                op[(size_t)(orow + j) * Wd + c0 + tx] =
                    num * __builtin_amdgcn_rcpf(den);
            }
        }

        if (k < 7) {
            __syncthreads();   // all S3 reads done before slots are overwritten

            // ---- S1: stage 64 new raw rows (global->reg->LDS, one phase) ----
            {
                int slot = base74 + i_row0; if (slot >= RS) slot -= RS;
                const int gr = growb + i_row0;
                float4 lx = make_float4(0.f, 0.f, 0.f, 0.f), ly = lx;
                if (okc0 && gr < Hd) {
                    const size_t gi = ((size_t)gr << 9) + gc0;
                    lx = *reinterpret_cast<const float4*>(xp + gi);
                    ly = *reinterpret_cast<const float4*>(yp + gi);
                }
                float* wp = &buf[0][0] + slot * PITCH + 8 * c40;
                *reinterpret_cast<float4*>(wp) =
                    make_float4(lx.x, ly.x, lx.y, ly.y);
                *reinterpret_cast<float4*>(wp + 4) =
                    make_float4(lx.z, ly.z, lx.w, ly.w);
            }
            if (tid < 256) {
                int slot = base74 + i_row1; if (slot >= RS) slot -= RS;
                const int gr = growb + i_row1;
                float4 lx = make_float4(0.f, 0.f, 0.f, 0.f), ly = lx;
                if (okc1 && gr < Hd) {
                    const size_t gi = ((size_t)gr << 9) + gc1;
                    lx = *reinterpret_cast<const float4*>(xp + gi);
                    ly = *reinterpret_cast<const float4*>(yp + gi);
                }
                float* wp = &buf[0][0] + slot * PITCH + 8 * c41;
                *reinterpret_cast<float4*>(wp) =
                    make_float4(lx.x, ly.x, lx.y, ly.y);
                *reinterpret_cast<float4*>(wp + 4) =
                    make_float4(lx.z, ly.z, lx.w, ly.w);
            }
            __syncthreads();

            // ---- S2: h-conv the 64 new rows in place (waves 0-3) ----
            if (tid < 256) {
                int slot = base74 + s2row; if (slot >= RS) slot -= RS;
                hconv8(buf, g, slot, s2cb);
            }
            __syncthreads();

            base74 += 64; if (base74 >= RS) base74 -= RS;
            growb  += 64;
        }
        orow += 64;
    }
}

extern "C" void kernel_launch(void* const* d_in, const int* in_sizes, int n_in,
                              void* d_out, int out_size, void* d_ws, size_t ws_size,
                              hipStream_t stream) {
    const float* img_out    = (const float*)d_in[0];
    const float* img_target = (const float*)d_in[1];
    // d_in[2] is window_size==11; fixed by the problem, baked into the kernel.
    float* out = (float*)d_out;

    dim3 grid(Wd / TX, 1, BC);   // 16 x 1 x 48 = 768 strips = 3/CU exactly
    ssim_kernel<<<grid, NT, 0, stream>>>(img_out, img_target, out);
}

// Round 12
// 59.368 us; speedup vs baseline: 1.0244x; 1.0244x over previous
//
#include <hip/hip_runtime.h>

// SSIM map — round-12: half-tile 4-phase pipeline (T14 inside phases).
// B=16, C=3, H=W=512, 11-tap separable gaussian (sigma=1.5).
//
// Base = round-10 (57.7us best): 32x64 tile, 512 thr, union LDS [74][164]f
// (48.5KB -> 3 blk/CU), pk_fma math, paired-xy, 8-col h-conv items,
// float4 staging, XCD-channel swizzle (FETCH at compulsory 49MB).
//
// Round-11 regressed (60.8, VALUBusy 46%): persistent strip serializes
// phases with no intra-block overlap partner. Round-10's residual: 66%
// VALU-busy, 34% idle = coarse barrier phases (S1 load-wait exposed;
// S3 on 4 waves only). This round splits the SAME tile into TOP (slots
// 0..41) / BOTTOM (slots 42..73) and co-schedules disjoint-slot tasks:
//   P1: stage TOP. bar.
//   P2: issue BOTTOM loads (waves0-5) || h-conv TOP (lanes>=344)
//       || write BOTTOM (vmcnt waits AFTER compute = T14, no regs
//       across barriers — round-8's scratch killer avoided). bar.
//   P3: h-conv BOTTOM (waves0-1) || v-conv+SSIM out rows 0..31
//       (needs hf slots <=41 only; waves 4-7). bar.
//   P4: v-conv+SSIM out rows 32..63 (slots 32..73; waves 0-3).
// Work totals and accumulation order identical to round-10 (bitwise-same).
// Tripwire: WRITE_SIZE must stay 49152 KB (jump = scratch demotion).

#define W     512
#define H     512
#define BC    48
#define TX    32
#define TY    64
#define TOPR  42          // slots 0..41 = rows r0-5 .. r0+36
#define BOTR  32          // slots 42..73 = rows r0+37 .. r0+68
#define IC4   12          // float4 cols staged per row (48 cols: c0-8..c0+39)
#define PITCH 164         // floats/row: 656B = 41 float4s (odd: bank stagger)
#define NT    512

__device__ __forceinline__ float2 pk_mul2(float2 a, float2 b) {
    float2 d;
    asm("v_pk_mul_f32 %0, %1, %2" : "=v"(d) : "v"(a), "v"(b));
    return d;
}
// acc = w*v + acc  (both lanes); w uniform -> SGPR pair
__device__ __forceinline__ void pk_fma2(float2& acc, float2 w, float2 v) {
    asm("v_pk_fma_f32 %0, %1, %2, %0" : "+v"(acc) : "s"(w), "v"(v));
}
// gaussian weight with zero padding outside [0,10] (compile-time folded)
__device__ __forceinline__ float gwf(const float* g, int m) {
    return (m >= 0 && m <= 10) ? g[m] : 0.f;
}

// 8-col horizontal conv of one raw row slot (in-place union write).
// Identical math/order to round-10 stage 2 (bitwise-same).
__device__ __forceinline__ void hconv8(float (*buf)[PITCH], const float* g,
                                       int row, int cb) {
    const float* __restrict__ rb = &buf[row][2 * cb + 4];

    float2 A01[8], A23[8], A4p[4];
#pragma unroll
    for (int j = 0; j < 8; ++j) {
        A01[j] = make_float2(0.f, 0.f);
        A23[j] = make_float2(0.f, 0.f);
    }
#pragma unroll
    for (int p = 0; p < 4; ++p) A4p[p] = make_float2(0.f, 0.f);

    float4 q4[10];
#pragma unroll
    for (int q = 0; q < 5; ++q)                  // batch A
        q4[q] = *reinterpret_cast<const float4*>(rb + 4 * q);
#pragma unroll
    for (int kk = 0; kk < 8; ++kk) {
        const float4 f = q4[(kk + 1) >> 1];
        const float2 vv = (kk & 1) ? make_float2(f.x, f.y)
                                   : make_float2(f.z, f.w);
        const float2 pp   = pk_mul2(vv, vv);
        const float  pxy  = vv.x * vv.y;
        const float2 pxy2 = make_float2(pxy, pxy);
#pragma unroll
        for (int j = 0; j < 8; ++j) {
            const int m = kk - j;
            if (m >= 0 && m <= 10) {
                const float2 w2 = make_float2(g[m], g[m]);
                pk_fma2(A01[j], w2, vv);
                pk_fma2(A23[j], w2, pp);
            }
        }
#pragma unroll
        for (int p = 0; p < 4; ++p) {
            const int m0 = kk - (p << 1);
            if (m0 >= 0 && m0 <= 11) {
                const float2 w2 = make_float2(gwf(g, m0), gwf(g, m0 - 1));
                pk_fma2(A4p[p], w2, pxy2);
            }
        }
    }
#pragma unroll
    for (int q = 5; q < 10; ++q)                 // batch B
        q4[q] = *reinterpret_cast<const float4*>(rb + 4 * q);
#pragma unroll
    for (int kk = 8; kk < 18; ++kk) {
        const float4 f = q4[(kk + 1) >> 1];
        const float2 vv = (kk & 1) ? make_float2(f.x, f.y)
                                   : make_float2(f.z, f.w);
        const float2 pp   = pk_mul2(vv, vv);
        const float  pxy  = vv.x * vv.y;
        const float2 pxy2 = make_float2(pxy, pxy);
#pragma unroll
        for (int j = 0; j < 8; ++j) {
            const int m = kk - j;
            if (m >= 0 && m <= 10) {
                const float2 w2 = make_float2(g[m], g[m]);
                pk_fma2(A01[j], w2, vv);
                pk_fma2(A23[j], w2, pp);
            }
        }
#pragma unroll
        for (int p = 0; p < 4; ++p) {
            const int m0 = kk - (p << 1);
            if (m0 >= 0 && m0 <= 11) {
                const float2 w2 = make_float2(gwf(g, m0), gwf(g, m0 - 1));
                pk_fma2(A4p[p], w2, pxy2);
            }
        }
    }
#pragma unroll
    for (int j = 0; j < 8; ++j) {
        *reinterpret_cast<float4*>(&buf[row][4 * (cb + j)]) =
            make_float4(A01[j].x, A01[j].y, A23[j].x, A23[j].y);
    }
    *reinterpret_cast<float4*>(&buf[row][128 + cb]) =
        make_float4(A4p[0].x, A4p[0].y, A4p[1].x, A4p[1].y);
    *reinterpret_cast<float4*>(&buf[row][128 + cb + 4]) =
        make_float4(A4p[2].x, A4p[2].y, A4p[3].x, A4p[3].y);
}

// v-conv + SSIM for 4 consecutive output rows og..og+3 at column tx.
// Reads hf slots og..og+13. Same tap order / pairing as round-10 (bitwise).
__device__ __forceinline__ void s3quad(const float (*buf)[PITCH],
                                       const float* g, float* __restrict__ op,
                                       int r0, int c0, int tx, int og) {
    float2 acc01[4], acc23[4], acc4p[2];
#pragma unroll
    for (int j = 0; j < 4; ++j) {
        acc01[j] = make_float2(0.f, 0.f);
        acc23[j] = make_float2(0.f, 0.f);
    }
#pragma unroll
    for (int p = 0; p < 2; ++p) acc4p[p] = make_float2(0.f, 0.f);

#pragma unroll
    for (int rr = 0; rr < 14; ++rr) {
        const float4 h4 =
            *reinterpret_cast<const float4*>(&buf[og + rr][4 * tx]);
        const float  h5 = buf[og + rr][128 + tx];
        const float2 h01 = make_float2(h4.x, h4.y);
        const float2 h23 = make_float2(h4.z, h4.w);
        const float2 h55 = make_float2(h5, h5);
#pragma unroll
        for (int j = 0; j < 4; ++j) {
            const int m = rr - j;
            if (m >= 0 && m <= 10) {
                const float2 w2 = make_float2(g[m], g[m]);
                pk_fma2(acc01[j], w2, h01);
                pk_fma2(acc23[j], w2, h23);
            }
        }
#pragma unroll
        for (int p = 0; p < 2; ++p) {
            const int m0 = rr - (p << 1);
            if (m0 >= 0 && m0 <= 11) {
                const float2 w2 = make_float2(gwf(g, m0), gwf(g, m0 - 1));
                pk_fma2(acc4p[p], w2, h55);
            }
        }
    }
#pragma unroll
    for (int j = 0; j < 4; ++j) {
        const float2 a01  = acc01[j];
        const float2 musq = pk_mul2(a01, a01);       // (mu1^2, mu2^2)
        const float  mu12 = a01.x * a01.y;
        const float  a4   = (j & 1) ? acc4p[j >> 1].y : acc4p[j >> 1].x;
        const float  s1   = acc23[j].x - musq.x;
        const float  s2   = acc23[j].y - musq.y;
        const float  s12  = a4 - mu12;
        const float num = fmaf(2.f, mu12, 1e-4f) * fmaf(2.f, s12, 9e-4f);
        const float den = ((musq.x + musq.y) + 1e-4f) * ((s1 + s2) + 9e-4f);
        op[(size_t)(r0 + og + j) * W + c0 + tx] =
            num * __builtin_amdgcn_rcpf(den);
    }
}

__global__ __launch_bounds__(NT, 6) void ssim_kernel(
    const float* __restrict__ x, const float* __restrict__ y,
    float* __restrict__ out)
{
    __shared__ __align__(16) float buf[TOPR + BOTR][PITCH];  // 48544 B

    // fp32-normalized gaussian, sigma=1.5, K=11 (matches np reference ~1e-7)
    const float g[11] = {
        0.00102838f, 0.00759875f, 0.03600077f, 0.10936069f, 0.21300553f,
        0.26601172f,
        0.21300553f, 0.10936069f, 0.03600077f, 0.00759875f, 0.00102838f};

    const int tid = threadIdx.x;

    // ---- XCD-channel swizzle: each XCD owns 6 whole channels ----
    const int lin  = blockIdx.x + (blockIdx.y << 4) + (blockIdx.z << 7);
    const int tile = ((lin & 7) * 768) + (lin >> 3);   // bijective, 6144=8*768
    const int bc   = tile >> 7;                        // channel 0..47
    const int tyi  = (tile >> 4) & 7;                  // tile row 0..7
    const int txi  = tile & 15;                        // tile col 0..15
    const int c0   = txi * TX;
    const int r0   = tyi * TY;

    const float* __restrict__ xp = x + (size_t)bc * H * W;
    const float* __restrict__ yp = y + (size_t)bc * H * W;
    float* __restrict__ op = out + (size_t)bc * H * W;

    const bool xin = (txi > 0) && (txi < (W / TX) - 1);

    // ---- P1: stage TOP — slots 0..41 = rows r0-5..r0+36 (504 items) ----
    if (tid < TOPR * IC4) {
        const int r  = tid / IC4;
        const int c4 = tid - r * IC4;
        const int gr = r0 - 5 + r;
        const int gc = c0 - 8 + 4 * c4;
        const bool ok = ((unsigned)gr < (unsigned)H) &&
                        (xin || ((unsigned)gc < (unsigned)W));
        float4 lx = make_float4(0.f, 0.f, 0.f, 0.f), ly = lx;
        if (ok) {
            const size_t gi = ((size_t)gr << 9) + gc;
            lx = *reinterpret_cast<const float4*>(xp + gi);
            ly = *reinterpret_cast<const float4*>(yp + gi);
        }
        *reinterpret_cast<float4*>(&buf[r][8 * c4]) =
            make_float4(lx.x, ly.x, lx.y, ly.y);
        *reinterpret_cast<float4*>(&buf[r][8 * c4 + 4]) =
            make_float4(lx.z, ly.z, lx.w, ly.w);
    }
    __syncthreads();

    // ---- P2: issue BOTTOM loads || h-conv TOP || write BOTTOM ----
    {
        // (a) issue loads for slots 42..73 = rows r0+37..r0+68 (384 items)
        float4 lbx, lby;
        int woff = 0;
        const bool havew = tid < BOTR * IC4;           // waves 0-5
        if (havew) {
            const int r32 = tid / IC4;
            const int c4  = tid - r32 * IC4;
            const int gr  = r0 + 37 + r32;
            const int gc  = c0 - 8 + 4 * c4;
            const bool ok = (gr < H) && (xin || ((unsigned)gc < (unsigned)W));
            lbx = make_float4(0.f, 0.f, 0.f, 0.f);
            lby = lbx;
            if (ok) {
                const size_t gi = ((size_t)gr << 9) + gc;
                lbx = *reinterpret_cast<const float4*>(xp + gi);
                lby = *reinterpret_cast<const float4*>(yp + gi);
            }
            woff = (TOPR + r32) * PITCH + 8 * c4;
        }
        // (b) h-conv TOP: 168 items on lanes 344..511 (rows wave-local,
        //     4 consecutive lanes per row -> in-place aliasing safe)
        if (tid >= NT - TOPR * 4) {                    // tid >= 344
            const int i = tid - (NT - TOPR * 4);
            hconv8(buf, g, i >> 2, (i & 3) << 3);
        }
        // (c) write BOTTOM raw (vmcnt wait lands here, after the compute)
        if (havew) {
            float* wp = &buf[0][0] + woff;
            *reinterpret_cast<float4*>(wp) =
                make_float4(lbx.x, lby.x, lbx.y, lby.y);
            *reinterpret_cast<float4*>(wp + 4) =
                make_float4(lbx.z, lby.z, lbx.w, lby.w);
        }
    }
    __syncthreads();

    // ---- P3: h-conv BOTTOM (waves 0-1) || v-conv TOP out rows 0..31 ----
    if (tid < BOTR * 4) {                              // 128 items
        hconv8(buf, g, TOPR + (tid >> 2), (tid & 3) << 3);
    } else if (tid >= 256) {                           // waves 4-7
        const int t = tid - 256;
        s3quad(buf, g, op, r0, c0, t & 31, (t >> 5) << 2);   // og 0..28
    }
    __syncthreads();

    // ---- P4: v-conv BOTTOM out rows 32..63 (waves 0-3) ----
    if (tid < 256) {
        s3quad(buf, g, op, r0, c0, tid & 31, 32 + ((tid >> 5) << 2));
    }
}

extern "C" void kernel_launch(void* const* d_in, const int* in_sizes, int n_in,
                              void* d_out, int out_size, void* d_ws, size_t ws_size,
                              hipStream_t stream) {
    const float* img_out    = (const float*)d_in[0];
    const float* img_target = (const float*)d_in[1];
    // d_in[2] is window_size==11; fixed by the problem, baked into the kernel.
    float* out = (float*)d_out;

    dim3 grid(W / TX, H / TY, BC);   // 16 x 8 x 48 = 6144 blocks
    ssim_kernel<<<grid, NT, 0, stream>>>(img_out, img_target, out);
}

// Round 13
// 46.161 us; speedup vs baseline: 1.3175x; 1.2861x over previous
//
#include <hip/hip_runtime.h>

// SSIM map — round-13: 4-channel algebra (S/D repack) -> 4 blocks/CU.
// B=16, C=3, H=W=512, 11-tap separable gaussian (sigma=1.5).
//
// Base = round-10 (57.7us best). Key change: SSIM needs only mu1, mu2,
// s1+s2, s12 — never s1/s2 separately. With per-pixel S = x^2+y^2 and
// D = (x-y)^2:
//   s1+s2    = conv(S) - mu1^2 - mu2^2
//   2*s12    = (conv(S) - conv(D)) - 2*mu1*mu2     [conv(xy)=(S-D)/2]
// -> FOUR conv channels, two perfect pk pairs (x,y) and (S,D); the scalar
// xy channel (hfx plane, 18 b32 reads/thread in S3, 44 pk_fma) vanishes.
//   * LDS row 164 -> 132 words (hf = 32 float4 only): 39072 B/block ->
//     4 blocks/CU = 32 waves (was 3/24) — the occupancy unlock.
//   * f4-pitch 33 (odd, ==1 mod 8): all conflict-free lane maps preserved.
//   * S3: -18 b32 reads, -44 pk_fma per thread; S2: -44 pk_fma - 2 writes,
//     +2 instr/tap product prep (net ~-3%).
// Numerics: pre-add/recombine shifts s-values ~1e-7 (S~0.66, D~0.17 — no
// new cancellation); ssim shift ~1e-6. absmax has been rcp-dominated and
// invariant across 12 rounds of math changes.
//
// Structure otherwise identical to round-10: 32x64 tile, 512 thr, union
// raw/hf LDS, 2 barriers, float4 stage-1 (aligned 48-col window), 8-col
// stage-2 items (wave-local rows -> in-place aliasing safe), 8-row
// stage-3 items (256 thr), XCD-channel swizzle (FETCH at compulsory).
// Rounds 8/11/12 (ring, strip, split-phase pipelining) all regressed —
// schedule axis abandoned; this attacks work + occupancy instead.

#define W     512
#define H     512
#define BC    48
#define TX    32
#define TY    64
#define IY    74          // TY + 10
#define IC4   12          // float4 cols staged per row (48 cols: c0-8..c0+39)
#define PITCH 132         // floats/row: 528B = 33 float4s (odd: bank stagger)
#define NT    512

__device__ __forceinline__ float2 pk_mul2(float2 a, float2 b) {
    float2 d;
    asm("v_pk_mul_f32 %0, %1, %2" : "=v"(d) : "v"(a), "v"(b));
    return d;
}
// acc = w*v + acc  (both lanes); w uniform -> SGPR pair
__device__ __forceinline__ void pk_fma2(float2& acc, float2 w, float2 v) {
    asm("v_pk_fma_f32 %0, %1, %2, %0" : "+v"(acc) : "s"(w), "v"(v));
}

__global__ __launch_bounds__(NT, 8) void ssim_kernel(
    const float* __restrict__ x, const float* __restrict__ y,
    float* __restrict__ out)
{
    __shared__ __align__(16) float buf[IY][PITCH];   // 39072 B -> 4 blocks/CU

    // fp32-normalized gaussian, sigma=1.5, K=11 (matches np reference ~1e-7)
    const float g[11] = {
        0.00102838f, 0.00759875f, 0.03600077f, 0.10936069f, 0.21300553f,
        0.26601172f,
        0.21300553f, 0.10936069f, 0.03600077f, 0.00759875f, 0.00102838f};

    const int tid = threadIdx.x;

    // ---- XCD-channel swizzle: each XCD owns 6 whole channels ----
    const int lin  = blockIdx.x + (blockIdx.y << 4) + (blockIdx.z << 7);
    const int tile = ((lin & 7) * 768) + (lin >> 3);   // bijective, 6144=8*768
    const int bc   = tile >> 7;                        // channel 0..47
    const int tyi  = (tile >> 4) & 7;                  // tile row 0..7
    const int txi  = tile & 15;                        // tile col 0..15
    const int c0   = txi * TX;
    const int r0   = tyi * TY;

    const float* __restrict__ xp = x + (size_t)bc * H * W;
    const float* __restrict__ yp = y + (size_t)bc * H * W;

    const bool xin = (txi > 0) && (txi < (W / TX) - 1);

    // ---- Stage 1: global float4 -> LDS interleaved (x,y) pairs ----
    // item = r*12 + c4; cols gc = c0-8+4*c4 (aligned, never straddles edge)
#pragma unroll
    for (int it = 0; it < 2; ++it) {
        const int idx = tid + it * NT;
        if (idx < IY * IC4) {
            const int r  = idx / IC4;
            const int c4 = idx - r * IC4;
            const int gr = r0 - 5 + r;
            const int gc = c0 - 8 + 4 * c4;
            const bool ok = ((unsigned)gr < (unsigned)H) &&
                            (xin || ((unsigned)gc < (unsigned)W));
            float4 lx = make_float4(0.f, 0.f, 0.f, 0.f), ly = lx;
            if (ok) {
                const size_t gi = ((size_t)gr << 9) + gc;
                lx = *reinterpret_cast<const float4*>(xp + gi);
                ly = *reinterpret_cast<const float4*>(yp + gi);
            }
            *reinterpret_cast<float4*>(&buf[r][8 * c4]) =
                make_float4(lx.x, ly.x, lx.y, ly.y);
            *reinterpret_cast<float4*>(&buf[r][8 * c4 + 4]) =
                make_float4(lx.z, ly.z, lx.w, ly.w);
        }
    }
    __syncthreads();

    // ---- Stage 2: horizontal conv, 8 consecutive cols per item ----
    // wave w<4: rows 16w..16w+15 (row-low = l&7, row-mid = l>>5, cg =
    // (l>>3)&3); wave 4 (lanes 0-39): rows 64-73, cg = l&3. Wave-local
    // rows + all-reads-before-writes -> in-place raw->hf aliasing safe.
    {
        const int l   = tid & 63;
        const int wid = tid >> 6;
        int row, cg;
        if (wid < 4) {
            row = (wid << 4) + ((l >> 5) << 3) + (l & 7);
            cg  = (l >> 3) & 3;
        } else {
            row = 64 + (l >> 2);
            cg  = l & 3;
        }
        const int  cb  = cg << 3;                  // base output col 0,8,16,24
        const bool act = (wid < 4) || ((wid == 4) && (l < 40));
        if (act) {
            // taps kk=0..17: local col cb+3+kk -> word 2cb+6+2kk;
            // b128 reads cover words 2cb+4 .. 2cb+43 (q = (kk+1)>>1).
            const float* __restrict__ rb = &buf[row][2 * cb + 4];

            float2 A01[8], ASD[8];
#pragma unroll
            for (int j = 0; j < 8; ++j) {
                A01[j] = make_float2(0.f, 0.f);
                ASD[j] = make_float2(0.f, 0.f);
            }

            float4 q4[10];
#pragma unroll
            for (int q = 0; q < 5; ++q)            // batch A
                q4[q] = *reinterpret_cast<const float4*>(rb + 4 * q);
#pragma unroll
            for (int kk = 0; kk < 8; ++kk) {
                const float4 f = q4[(kk + 1) >> 1];
                const float2 vv = (kk & 1) ? make_float2(f.x, f.y)
                                           : make_float2(f.z, f.w);
                const float2 pp = pk_mul2(vv, vv);       // (xx, yy)
                const float  t  = vv.x * vv.y;           // xy
                const float  Sv = pp.x + pp.y;           // x^2 + y^2
                const float  Dv = fmaf(-2.f, t, Sv);     // (x - y)^2
                const float2 qq = make_float2(Sv, Dv);
#pragma unroll
                for (int j = 0; j < 8; ++j) {
                    const int m = kk - j;
                    if (m >= 0 && m <= 10) {
                        const float2 w2 = make_float2(g[m], g[m]);
                        pk_fma2(A01[j], w2, vv);
                        pk_fma2(ASD[j], w2, qq);
                    }
                }
            }
#pragma unroll
            for (int q = 5; q < 10; ++q)           // batch B
                q4[q] = *reinterpret_cast<const float4*>(rb + 4 * q);
#pragma unroll
            for (int kk = 8; kk < 18; ++kk) {
                const float4 f = q4[(kk + 1) >> 1];
                const float2 vv = (kk & 1) ? make_float2(f.x, f.y)
                                           : make_float2(f.z, f.w);
                const float2 pp = pk_mul2(vv, vv);
                const float  t  = vv.x * vv.y;
                const float  Sv = pp.x + pp.y;
                const float  Dv = fmaf(-2.f, t, Sv);
                const float2 qq = make_float2(Sv, Dv);
#pragma unroll
                for (int j = 0; j < 8; ++j) {
                    const int m = kk - j;
                    if (m >= 0 && m <= 10) {
                        const float2 w2 = make_float2(g[m], g[m]);
                        pk_fma2(A01[j], w2, vv);
                        pk_fma2(ASD[j], w2, qq);
                    }
                }
            }
            // hf: (xbar, ybar, Sbar, Dbar) at words 4*(cb+j), j=0..7
#pragma unroll
            for (int j = 0; j < 8; ++j) {
                *reinterpret_cast<float4*>(&buf[row][4 * (cb + j)]) =
                    make_float4(A01[j].x, A01[j].y, ASD[j].x, ASD[j].y);
            }
        }
    }
    __syncthreads();

    // ---- Stage 3: vertical conv + SSIM, 8 consecutive rows per thread ----
    // 256 active threads: tx = tid&31 (col), og = (tid>>5)*8 (rows og..og+7).
    if (tid < 256) {
        const int tx = tid & 31;
        const int og = (tid >> 5) << 3;          // first output row 0,8,..,56

        float2 acc01[8], accSD[8];
#pragma unroll
        for (int j = 0; j < 8; ++j) {
            acc01[j] = make_float2(0.f, 0.f);
            accSD[j] = make_float2(0.f, 0.f);
        }

#pragma unroll
        for (int rr = 0; rr < 18; ++rr) {
            const float4 h4 =
                *reinterpret_cast<const float4*>(&buf[og + rr][4 * tx]);
            const float2 h01 = make_float2(h4.x, h4.y);
            const float2 hSD = make_float2(h4.z, h4.w);
#pragma unroll
            for (int j = 0; j < 8; ++j) {
                const int m = rr - j;            // tap index for output j
                if (m >= 0 && m <= 10) {
                    const float2 w2 = make_float2(g[m], g[m]);
                    pk_fma2(acc01[j], w2, h01);
                    pk_fma2(accSD[j], w2, hSD);
                }
            }
        }

        float* __restrict__ op = out + (size_t)bc * H * W;
#pragma unroll
        for (int j = 0; j < 8; ++j) {
            const float2 a01  = acc01[j];
            const float2 musq = pk_mul2(a01, a01);     // (mu1^2, mu2^2)
            const float  mu12 = a01.x * a01.y;
            const float  msum = musq.x + musq.y;       // mu1^2 + mu2^2
            const float  Sv   = accSD[j].x;            // conv(x^2 + y^2)
            const float  Dv   = accSD[j].y;            // conv((x-y)^2)
            const float  sd   = Sv - Dv;               // 2*conv(xy)
            const float  t2   = fmaf(-2.f, mu12, sd);  // 2*s12
            const float num = fmaf(2.f, mu12, 1e-4f) * (t2 + 9e-4f);
            const float den = (msum + 1e-4f) * ((Sv - msum) + 9e-4f);
            op[(size_t)(r0 + og + j) * W + c0 + tx] =
                num * __builtin_amdgcn_rcpf(den);
        }
    }
}

extern "C" void kernel_launch(void* const* d_in, const int* in_sizes, int n_in,
                              void* d_out, int out_size, void* d_ws, size_t ws_size,
                              hipStream_t stream) {
    const float* img_out    = (const float*)d_in[0];
    const float* img_target = (const float*)d_in[1];
    // d_in[2] is window_size==11; fixed by the problem, baked into the kernel.
    float* out = (float*)d_out;

    dim3 grid(W / TX, H / TY, BC);   // 16 x 8 x 48 = 6144 blocks
    ssim_kernel<<<grid, NT, 0, stream>>>(img_out, img_target, out);
}

// Round 14
// 44.721 us; speedup vs baseline: 1.3599x; 1.0322x over previous
//
#include <hip/hip_runtime.h>

// SSIM map — round-14: (u,v)=(x+y,x-y) basis rotation — zero-prep stage 2.
// B=16, C=3, H=W=512, 11-tap separable gaussian (sigma=1.5).
//
// Base = round-13 (46.2us): 4-channel S/D algebra, 32x64 tile, 512 thr,
// union LDS [74][132]f (39.1KB -> 4 blk/CU), 2 barriers, pk_fma core,
// 8-col S2 items, 8-row S3 items, XCD-channel swizzle.
//
// Round-13 residual: VALU ~70% of real runtime — instruction count bound.
// S2 still pays ~5 VALU/tap building the (S,D) packed operand. Fix: stage
// u=x+y, v=x-y. Then x^2+y^2=(u^2+v^2)/2, (x-y)^2=v^2, xy=(u^2-v^2)/4:
// conv channels become (u,v) and (u^2,v^2) — stage-2 per-tap prep is ONE
// pk_mul(vv,vv) (result already an aligned pair; no scalar ops/marshal):
// ~-25k lane-ops/block. Stage-1: +8 add/sub per item (hidden under loads).
// Epilogue recombination (exact pow2 halvings):
//   2*mu12        = (cu^2 - cv^2)/2
//   mu1^2+mu2^2   = (cu^2 + cv^2)/2
//   2*s12         = ((cU - cV) - (cu^2 - cv^2))/2
//   s1+s2         = ((cU + cV) - (cu^2 + cv^2))/2
// (cu,cv = 2D-conv of u,v; cU,cV = 2D-conv of u^2,v^2.)
// u,v are 1-ulp sums/差 of [0,1) values — same error scale as r13's S/D
// repack (absmax invariant there). All layout/lane maps byte-identical.

#define W     512
#define H     512
#define BC    48
#define TX    32
#define TY    64
#define IY    74          // TY + 10
#define IC4   12          // float4 cols staged per row (48 cols: c0-8..c0+39)
#define PITCH 132         // floats/row: 528B = 33 float4s (odd: bank stagger)
#define NT    512

__device__ __forceinline__ float2 pk_mul2(float2 a, float2 b) {
    float2 d;
    asm("v_pk_mul_f32 %0, %1, %2" : "=v"(d) : "v"(a), "v"(b));
    return d;
}
// acc = w*v + acc  (both lanes); w uniform -> SGPR pair
__device__ __forceinline__ void pk_fma2(float2& acc, float2 w, float2 v) {
    asm("v_pk_fma_f32 %0, %1, %2, %0" : "+v"(acc) : "s"(w), "v"(v));
}

__global__ __launch_bounds__(NT, 8) void ssim_kernel(
    const float* __restrict__ x, const float* __restrict__ y,
    float* __restrict__ out)
{
    __shared__ __align__(16) float buf[IY][PITCH];   // 39072 B -> 4 blocks/CU

    // fp32-normalized gaussian, sigma=1.5, K=11 (matches np reference ~1e-7)
    const float g[11] = {
        0.00102838f, 0.00759875f, 0.03600077f, 0.10936069f, 0.21300553f,
        0.26601172f,
        0.21300553f, 0.10936069f, 0.03600077f, 0.00759875f, 0.00102838f};

    const int tid = threadIdx.x;

    // ---- XCD-channel swizzle: each XCD owns 6 whole channels ----
    const int lin  = blockIdx.x + (blockIdx.y << 4) + (blockIdx.z << 7);
    const int tile = ((lin & 7) * 768) + (lin >> 3);   // bijective, 6144=8*768
    const int bc   = tile >> 7;                        // channel 0..47
    const int tyi  = (tile >> 4) & 7;                  // tile row 0..7
    const int txi  = tile & 15;                        // tile col 0..15
    const int c0   = txi * TX;
    const int r0   = tyi * TY;

    const float* __restrict__ xp = x + (size_t)bc * H * W;
    const float* __restrict__ yp = y + (size_t)bc * H * W;

    const bool xin = (txi > 0) && (txi < (W / TX) - 1);

    // ---- Stage 1: global float4 -> LDS interleaved (u,v) pairs ----
    // item = r*12 + c4; cols gc = c0-8+4*c4 (aligned, never straddles edge)
#pragma unroll
    for (int it = 0; it < 2; ++it) {
        const int idx = tid + it * NT;
        if (idx < IY * IC4) {
            const int r  = idx / IC4;
            const int c4 = idx - r * IC4;
            const int gr = r0 - 5 + r;
            const int gc = c0 - 8 + 4 * c4;
            const bool ok = ((unsigned)gr < (unsigned)H) &&
                            (xin || ((unsigned)gc < (unsigned)W));
            float4 lx = make_float4(0.f, 0.f, 0.f, 0.f), ly = lx;
            if (ok) {
                const size_t gi = ((size_t)gr << 9) + gc;
                lx = *reinterpret_cast<const float4*>(xp + gi);
                ly = *reinterpret_cast<const float4*>(yp + gi);
            }
            // u = x+y, v = x-y per pixel; store (u0,v0,u1,v1 | u2,v2,u3,v3)
            *reinterpret_cast<float4*>(&buf[r][8 * c4]) =
                make_float4(lx.x + ly.x, lx.x - ly.x,
                            lx.y + ly.y, lx.y - ly.y);
            *reinterpret_cast<float4*>(&buf[r][8 * c4 + 4]) =
                make_float4(lx.z + ly.z, lx.z - ly.z,
                            lx.w + ly.w, lx.w - ly.w);
        }
    }
    __syncthreads();

    // ---- Stage 2: horizontal conv, 8 consecutive cols per item ----
    // wave w<4: rows 16w..16w+15 (row-low = l&7, row-mid = l>>5, cg =
    // (l>>3)&3); wave 4 (lanes 0-39): rows 64-73, cg = l&3. Wave-local
    // rows + all-reads-before-writes -> in-place raw->hf aliasing safe.
    {
        const int l   = tid & 63;
        const int wid = tid >> 6;
        int row, cg;
        if (wid < 4) {
            row = (wid << 4) + ((l >> 5) << 3) + (l & 7);
            cg  = (l >> 3) & 3;
        } else {
            row = 64 + (l >> 2);
            cg  = l & 3;
        }
        const int  cb  = cg << 3;                  // base output col 0,8,16,24
        const bool act = (wid < 4) || ((wid == 4) && (l < 40));
        if (act) {
            // taps kk=0..17: local col cb+3+kk -> word 2cb+6+2kk;
            // b128 reads cover words 2cb+4 .. 2cb+43 (q = (kk+1)>>1).
            const float* __restrict__ rb = &buf[row][2 * cb + 4];

            float2 A01[8], AUV[8];
#pragma unroll
            for (int j = 0; j < 8; ++j) {
                A01[j] = make_float2(0.f, 0.f);
                AUV[j] = make_float2(0.f, 0.f);
            }

            float4 q4[10];
#pragma unroll
            for (int q = 0; q < 5; ++q)            // batch A
                q4[q] = *reinterpret_cast<const float4*>(rb + 4 * q);
#pragma unroll
            for (int kk = 0; kk < 8; ++kk) {
                const float4 f = q4[(kk + 1) >> 1];
                const float2 vv = (kk & 1) ? make_float2(f.x, f.y)
                                           : make_float2(f.z, f.w);
                const float2 qq = pk_mul2(vv, vv);       // (u^2, v^2)
#pragma unroll
                for (int j = 0; j < 8; ++j) {
                    const int m = kk - j;
                    if (m >= 0 && m <= 10) {
                        const float2 w2 = make_float2(g[m], g[m]);
                        pk_fma2(A01[j], w2, vv);
                        pk_fma2(AUV[j], w2, qq);
                    }
                }
            }
#pragma unroll
            for (int q = 5; q < 10; ++q)           // batch B
                q4[q] = *reinterpret_cast<const float4*>(rb + 4 * q);
#pragma unroll
            for (int kk = 8; kk < 18; ++kk) {
                const float4 f = q4[(kk + 1) >> 1];
                const float2 vv = (kk & 1) ? make_float2(f.x, f.y)
                                           : make_float2(f.z, f.w);
                const float2 qq = pk_mul2(vv, vv);
#pragma unroll
                for (int j = 0; j < 8; ++j) {
                    const int m = kk - j;
                    if (m >= 0 && m <= 10) {
                        const float2 w2 = make_float2(g[m], g[m]);
                        pk_fma2(A01[j], w2, vv);
                        pk_fma2(AUV[j], w2, qq);
                    }
                }
            }
            // hf: (ubar, vbar, U=conv(u^2), V=conv(v^2)) at words 4*(cb+j)
#pragma unroll
            for (int j = 0; j < 8; ++j) {
                *reinterpret_cast<float4*>(&buf[row][4 * (cb + j)]) =
                    make_float4(A01[j].x, A01[j].y, AUV[j].x, AUV[j].y);
            }
        }
    }
    __syncthreads();

    // ---- Stage 3: vertical conv + SSIM, 8 consecutive rows per thread ----
    // 256 active threads: tx = tid&31 (col), og = (tid>>5)*8 (rows og..og+7).
    if (tid < 256) {
        const int tx = tid & 31;
        const int og = (tid >> 5) << 3;          // first output row 0,8,..,56

        float2 acc01[8], accUV[8];
#pragma unroll
        for (int j = 0; j < 8; ++j) {
            acc01[j] = make_float2(0.f, 0.f);
            accUV[j] = make_float2(0.f, 0.f);
        }

#pragma unroll
        for (int rr = 0; rr < 18; ++rr) {
            const float4 h4 =
                *reinterpret_cast<const float4*>(&buf[og + rr][4 * tx]);
            const float2 h01 = make_float2(h4.x, h4.y);
            const float2 hUV = make_float2(h4.z, h4.w);
#pragma unroll
            for (int j = 0; j < 8; ++j) {
                const int m = rr - j;            // tap index for output j
                if (m >= 0 && m <= 10) {
                    const float2 w2 = make_float2(g[m], g[m]);
                    pk_fma2(acc01[j], w2, h01);
                    pk_fma2(accUV[j], w2, hUV);
                }
            }
        }

        float* __restrict__ op = out + (size_t)bc * H * W;
#pragma unroll
        for (int j = 0; j < 8; ++j) {
            const float2 a01 = acc01[j];               // (cu, cv)
            const float2 Q   = pk_mul2(a01, a01);      // (cu^2, cv^2)
            const float  Rm  = Q.x - Q.y;              // cu^2 - cv^2
            const float  Rp  = Q.x + Q.y;              // cu^2 + cv^2
            const float  Hm  = accUV[j].x - accUV[j].y;   // cU - cV
            const float  Hp  = accUV[j].x + accUV[j].y;   // cU + cV
            // num = (2*mu12 + C1)(2*s12 + C2); den = (musq + C1)(ssum + C2)
            const float num_a = fmaf(0.5f, Rm, 1e-4f);
            const float num_b = fmaf(0.5f, Hm - Rm, 9e-4f);
            const float den_a = fmaf(0.5f, Rp, 1e-4f);
            const float den_b = fmaf(0.5f, Hp - Rp, 9e-4f);
            op[(size_t)(r0 + og + j) * W + c0 + tx] =
                (num_a * num_b) * __builtin_amdgcn_rcpf(den_a * den_b);
        }
    }
}

extern "C" void kernel_launch(void* const* d_in, const int* in_sizes, int n_in,
                              void* d_out, int out_size, void* d_ws, size_t ws_size,
                              hipStream_t stream) {
    const float* img_out    = (const float*)d_in[0];
    const float* img_target = (const float*)d_in[1];
    // d_in[2] is window_size==11; fixed by the problem, baked into the kernel.
    float* out = (float*)d_out;

    dim3 grid(W / TX, H / TY, BC);   // 16 x 8 x 48 = 6144 blocks
    ssim_kernel<<<grid, NT, 0, stream>>>(img_out, img_target, out);
}

// Round 15
// 44.373 us; speedup vs baseline: 1.3705x; 1.0078x over previous
//
#include <hip/hip_runtime.h>

// SSIM map — round-15: first-tap-assign accumulators (kill zero-init movs).
// B=16, C=3, H=W=512, 11-tap separable gaussian (sigma=1.5).
//
// Base = round-14 (44.7us): (u,v)=(x+y,x-y) basis, 4 conv channels as two
// pk pairs, 32x64 tile, 512 thr, union LDS [74][132]f (39.1KB -> 4 blk/CU),
// 2 barriers, 8-col S2 items, 8-row S3 items, XCD-channel swizzle
// (FETCH/WRITE at compulsory 49/49MB).
//
// Residual: VALU ~55% busy (~31us) is the largest term; LDS ~50%; HBM 22%.
// Schedule redesigns r8/r11/r12 all regressed — instruction diet is the
// only productive axis. Remaining identified fat: 16 float2 acc zero-inits
// (32 v_mov) per S2 item and S3 thread ≈ 5-6% of the stream. Fix: assign
// on first tap (kk==j / rr==j, m=0) via pk_mul; taps m>=1 keep pk_fma.
// fma(a,b,+0) == round(a*b) bitwise for all finite inputs except an
// underflowed -0 product, which the next accumulate/epilogue squares erase
// -> output unchanged.
//
// Pre-commitment: if this gains <3%, the structure is at its practical
// ceiling (HBM compulsory, no pipe >60%, schedule axis triple-refuted) and
// the next call is ROOFLINE.

#define W     512
#define H     512
#define BC    48
#define TX    32
#define TY    64
#define IY    74          // TY + 10
#define IC4   12          // float4 cols staged per row (48 cols: c0-8..c0+39)
#define PITCH 132         // floats/row: 528B = 33 float4s (odd: bank stagger)
#define NT    512

__device__ __forceinline__ float2 pk_mul2(float2 a, float2 b) {
    float2 d;
    asm("v_pk_mul_f32 %0, %1, %2" : "=v"(d) : "v"(a), "v"(b));
    return d;
}
// d = s*v, s uniform (SGPR pair) — first-tap assign
__device__ __forceinline__ float2 pk_mul2s(float2 s, float2 v) {
    float2 d;
    asm("v_pk_mul_f32 %0, %1, %2" : "=v"(d) : "s"(s), "v"(v));
    return d;
}
// acc = w*v + acc  (both lanes); w uniform -> SGPR pair
__device__ __forceinline__ void pk_fma2(float2& acc, float2 w, float2 v) {
    asm("v_pk_fma_f32 %0, %1, %2, %0" : "+v"(acc) : "s"(w), "v"(v));
}

__global__ __launch_bounds__(NT, 8) void ssim_kernel(
    const float* __restrict__ x, const float* __restrict__ y,
    float* __restrict__ out)
{
    __shared__ __align__(16) float buf[IY][PITCH];   // 39072 B -> 4 blocks/CU

    // fp32-normalized gaussian, sigma=1.5, K=11 (matches np reference ~1e-7)
    const float g[11] = {
        0.00102838f, 0.00759875f, 0.03600077f, 0.10936069f, 0.21300553f,
        0.26601172f,
        0.21300553f, 0.10936069f, 0.03600077f, 0.00759875f, 0.00102838f};

    const int tid = threadIdx.x;

    // ---- XCD-channel swizzle: each XCD owns 6 whole channels ----
    const int lin  = blockIdx.x + (blockIdx.y << 4) + (blockIdx.z << 7);
    const int tile = ((lin & 7) * 768) + (lin >> 3);   // bijective, 6144=8*768
    const int bc   = tile >> 7;                        // channel 0..47
    const int tyi  = (tile >> 4) & 7;                  // tile row 0..7
    const int txi  = tile & 15;                        // tile col 0..15
    const int c0   = txi * TX;
    const int r0   = tyi * TY;

    const float* __restrict__ xp = x + (size_t)bc * H * W;
    const float* __restrict__ yp = y + (size_t)bc * H * W;

    const bool xin = (txi > 0) && (txi < (W / TX) - 1);

    // ---- Stage 1: global float4 -> LDS interleaved (u,v) pairs ----
    // item = r*12 + c4; cols gc = c0-8+4*c4 (aligned, never straddles edge)
#pragma unroll
    for (int it = 0; it < 2; ++it) {
        const int idx = tid + it * NT;
        if (idx < IY * IC4) {
            const int r  = idx / IC4;
            const int c4 = idx - r * IC4;
            const int gr = r0 - 5 + r;
            const int gc = c0 - 8 + 4 * c4;
            const bool ok = ((unsigned)gr < (unsigned)H) &&
                            (xin || ((unsigned)gc < (unsigned)W));
            float4 lx = make_float4(0.f, 0.f, 0.f, 0.f), ly = lx;
            if (ok) {
                const size_t gi = ((size_t)gr << 9) + gc;
                lx = *reinterpret_cast<const float4*>(xp + gi);
                ly = *reinterpret_cast<const float4*>(yp + gi);
            }
            // u = x+y, v = x-y per pixel; store (u0,v0,u1,v1 | u2,v2,u3,v3)
            *reinterpret_cast<float4*>(&buf[r][8 * c4]) =
                make_float4(lx.x + ly.x, lx.x - ly.x,
                            lx.y + ly.y, lx.y - ly.y);
            *reinterpret_cast<float4*>(&buf[r][8 * c4 + 4]) =
                make_float4(lx.z + ly.z, lx.z - ly.z,
                            lx.w + ly.w, lx.w - ly.w);
        }
    }
    __syncthreads();

    // ---- Stage 2: horizontal conv, 8 consecutive cols per item ----
    // wave w<4: rows 16w..16w+15 (row-low = l&7, row-mid = l>>5, cg =
    // (l>>3)&3); wave 4 (lanes 0-39): rows 64-73, cg = l&3. Wave-local
    // rows + all-reads-before-writes -> in-place raw->hf aliasing safe.
    {
        const int l   = tid & 63;
        const int wid = tid >> 6;
        int row, cg;
        if (wid < 4) {
            row = (wid << 4) + ((l >> 5) << 3) + (l & 7);
            cg  = (l >> 3) & 3;
        } else {
            row = 64 + (l >> 2);
            cg  = l & 3;
        }
        const int  cb  = cg << 3;                  // base output col 0,8,16,24
        const bool act = (wid < 4) || ((wid == 4) && (l < 40));
        if (act) {
            // taps kk=0..17: local col cb+3+kk -> word 2cb+6+2kk;
            // b128 reads cover words 2cb+4 .. 2cb+43 (q = (kk+1)>>1).
            const float* __restrict__ rb = &buf[row][2 * cb + 4];

            float2 A01[8], AUV[8];                 // assigned at first tap kk==j

            float4 q4[10];
#pragma unroll
            for (int q = 0; q < 5; ++q)            // batch A
                q4[q] = *reinterpret_cast<const float4*>(rb + 4 * q);
#pragma unroll
            for (int kk = 0; kk < 8; ++kk) {
                const float4 f = q4[(kk + 1) >> 1];
                const float2 vv = (kk & 1) ? make_float2(f.x, f.y)
                                           : make_float2(f.z, f.w);
                const float2 qq = pk_mul2(vv, vv);       // (u^2, v^2)
#pragma unroll
                for (int j = 0; j < 8; ++j) {
                    const int m = kk - j;
                    if (m == 0) {                        // first tap: assign
                        const float2 w2 = make_float2(g[0], g[0]);
                        A01[j] = pk_mul2s(w2, vv);
                        AUV[j] = pk_mul2s(w2, qq);
                    } else if (m >= 1 && m <= 10) {
                        const float2 w2 = make_float2(g[m], g[m]);
                        pk_fma2(A01[j], w2, vv);
                        pk_fma2(AUV[j], w2, qq);
                    }
                }
            }
#pragma unroll
            for (int q = 5; q < 10; ++q)           // batch B
                q4[q] = *reinterpret_cast<const float4*>(rb + 4 * q);
#pragma unroll
            for (int kk = 8; kk < 18; ++kk) {      // m >= 1 always here
                const float4 f = q4[(kk + 1) >> 1];
                const float2 vv = (kk & 1) ? make_float2(f.x, f.y)
                                           : make_float2(f.z, f.w);
                const float2 qq = pk_mul2(vv, vv);
#pragma unroll
                for (int j = 0; j < 8; ++j) {
                    const int m = kk - j;
                    if (m >= 1 && m <= 10) {
                        const float2 w2 = make_float2(g[m], g[m]);
                        pk_fma2(A01[j], w2, vv);
                        pk_fma2(AUV[j], w2, qq);
                    }
                }
            }
            // hf: (ubar, vbar, U=conv(u^2), V=conv(v^2)) at words 4*(cb+j)
#pragma unroll
            for (int j = 0; j < 8; ++j) {
                *reinterpret_cast<float4*>(&buf[row][4 * (cb + j)]) =
                    make_float4(A01[j].x, A01[j].y, AUV[j].x, AUV[j].y);
            }
        }
    }
    __syncthreads();

    // ---- Stage 3: vertical conv + SSIM, 8 consecutive rows per thread ----
    // 256 active threads: tx = tid&31 (col), og = (tid>>5)*8 (rows og..og+7).
    if (tid < 256) {
        const int tx = tid & 31;
        const int og = (tid >> 5) << 3;          // first output row 0,8,..,56

        float2 acc01[8], accUV[8];               // assigned at first tap rr==j

#pragma unroll
        for (int rr = 0; rr < 18; ++rr) {
            const float4 h4 =
                *reinterpret_cast<const float4*>(&buf[og + rr][4 * tx]);
            const float2 h01 = make_float2(h4.x, h4.y);
            const float2 hUV = make_float2(h4.z, h4.w);
#pragma unroll
            for (int j = 0; j < 8; ++j) {
                const int m = rr - j;            // tap index for output j
                if (m == 0) {                    // first tap: assign
                    const float2 w2 = make_float2(g[0], g[0]);
                    acc01[j] = pk_mul2s(w2, h01);
                    accUV[j] = pk_mul2s(w2, hUV);
                } else if (m >= 1 && m <= 10) {
                    const float2 w2 = make_float2(g[m], g[m]);
                    pk_fma2(acc01[j], w2, h01);
                    pk_fma2(accUV[j], w2, hUV);
                }
            }
        }

        float* __restrict__ op = out + (size_t)bc * H * W;
#pragma unroll
        for (int j = 0; j < 8; ++j) {
            const float2 a01 = acc01[j];               // (cu, cv)
            const float2 Q   = pk_mul2(a01, a01);      // (cu^2, cv^2)
            const float  Rm  = Q.x - Q.y;              // cu^2 - cv^2
            const float  Rp  = Q.x + Q.y;              // cu^2 + cv^2
            const float  Hm  = accUV[j].x - accUV[j].y;   // cU - cV
            const float  Hp  = accUV[j].x + accUV[j].y;   // cU + cV
            // num = (2*mu12 + C1)(2*s12 + C2); den = (musq + C1)(ssum + C2)
            const float num_a = fmaf(0.5f, Rm, 1e-4f);
            const float num_b = fmaf(0.5f, Hm - Rm, 9e-4f);
            const float den_a = fmaf(0.5f, Rp, 1e-4f);
            const float den_b = fmaf(0.5f, Hp - Rp, 9e-4f);
            op[(size_t)(r0 + og + j) * W + c0 + tx] =
                (num_a * num_b) * __builtin_amdgcn_rcpf(den_a * den_b);
        }
    }
}

extern "C" void kernel_launch(void* const* d_in, const int* in_sizes, int n_in,
                              void* d_out, int out_size, void* d_ws, size_t ws_size,
                              hipStream_t stream) {
    const float* img_out    = (const float*)d_in[0];
    const float* img_target = (const float*)d_in[1];
    // d_in[2] is window_size==11; fixed by the problem, baked into the kernel.
    float* out = (float*)d_out;

    dim3 grid(W / TX, H / TY, BC);   // 16 x 8 x 48 = 6144 blocks
    ssim_kernel<<<grid, NT, 0, stream>>>(img_out, img_target, out);
}